// Round 1
// baseline (757.335 us; speedup 1.0000x reference)
//
#include <hip/hip_runtime.h>
#include <hip/hip_bf16.h>
#include <math.h>

// mLSTM chunked forward, fp32 baseline (correctness-first).
// B=4 H=8 T=4096 K=V=128, BT=64 chunks, NT=64.

#define LOG2E 1.4426950408889634f
constexpr int Bsz = 4, Hsz = 8, Tsz = 4096, Ksz = 128, Vsz = 128;
constexpr int BT = 64, NT = 64, BH = Bsz * Hsz;
constexpr float SCALE = 0.08838834764831845f; // 128^-0.5
constexpr int VS = 8, VSL = Vsz / VS;         // V-slices for inter kernel

// ---------------- kernel 1: gate preprocessing per (bh, chunk) ----------------
// vecB = incl-cumsum(log2sigmoid(f)), vecA = I + (G - B), mintra = B_i + max_{j<=i}(I_j - B_j)
__global__ __launch_bounds__(64) void k_gates(
    const float* __restrict__ ig, const float* __restrict__ fg,
    float* __restrict__ vecB, float* __restrict__ vecI, float* __restrict__ vecA,
    float* __restrict__ mintra, float* __restrict__ scaG, float* __restrict__ scaA)
{
    int c = blockIdx.x, bh = blockIdx.y, lane = threadIdx.x;
    int t = bh * Tsz + c * BT + lane;
    float f = fg[t];
    float ls = fminf(f, 0.f) - log1pf(expf(-fabsf(f)));  // log_sigmoid, stable
    float vF = ls * LOG2E;
    float vI = ig[t] * LOG2E;
    // inclusive prefix sum of vF over the 64-lane wave
    float b = vF;
    #pragma unroll
    for (int off = 1; off < 64; off <<= 1) {
        float o = __shfl_up(b, off, 64);
        if (lane >= off) b += o;
    }
    float g = __shfl(b, 63, 64);   // chunk total decay
    // inclusive prefix max of (vI - b)
    float mi = vI - b;
    #pragma unroll
    for (int off = 1; off < 64; off <<= 1) {
        float o = __shfl_up(mi, off, 64);
        if (lane >= off) mi = fmaxf(mi, o);
    }
    float a = vI + g - b;
    vecB[t] = b; vecI[t] = vI; vecA[t] = a; mintra[t] = b + mi;
    // chunk max of a (for the m-scan)
    float am = a;
    #pragma unroll
    for (int off = 32; off; off >>= 1) am = fmaxf(am, __shfl_xor(am, off, 64));
    if (lane == 0) { scaG[bh * NT + c] = g; scaA[bh * NT + c] = am; }
}

// ---------------- kernel 2: m stabilizer scan (max-plus, associative) ----------------
// op_c: m -> max(m + g_c, amax_c). Compose via wave scan; mp[c] = m entering chunk c.
__global__ __launch_bounds__(64) void k_mscan(
    const float* __restrict__ scaG, const float* __restrict__ scaA, float* __restrict__ mp)
{
    int bh = blockIdx.x, lane = threadIdx.x;
    float a = scaG[bh * NT + lane];
    float b = scaA[bh * NT + lane];
    #pragma unroll
    for (int off = 1; off < 64; off <<= 1) {
        float ap = __shfl_up(a, off, 64);
        float bp = __shfl_up(b, off, 64);
        if (lane >= off) { b = fmaxf(bp + a, b); a = ap + a; }
    }
    if (lane == 0) mp[bh * (NT + 1)] = 0.f;
    mp[bh * (NT + 1) + lane + 1] = fmaxf(a, b); // m after chunk `lane` (m0 = 0)
}

// ---------------- kernel 3: sequential inter-chunk recurrence + consumption ----------------
// One block per (bh, v-slice of 16 cols). C slice [128][16] lives in LDS across chunks.
// Writes out[t][v] = qbar @ Cp  (state BEFORE update), denI (s==0 only) = qbar . np.
__global__ __launch_bounds__(256) void k_inter(
    const float* __restrict__ q, const float* __restrict__ k, const float* __restrict__ v,
    const float* __restrict__ vecB, const float* __restrict__ vecA,
    const float* __restrict__ mintra, const float* __restrict__ scaG,
    const float* __restrict__ mp, float* __restrict__ denI, float* __restrict__ out)
{
    int s = blockIdx.x, bh = blockIdx.y, tid = threadIdx.x;

    __shared__ float Cs[Ksz][VSL + 1];   // state slice
    __shared__ float nS[Ksz];
    __shared__ float qb[BT][Ksz + 1];    // qbar (scaled q)
    __shared__ float kb[BT][Ksz + 1];    // kbar (scaled k)
    __shared__ float vsl[BT][VSL + 1];
    __shared__ float sfq[BT], sfk[BT];

    for (int e = tid; e < Ksz * VSL; e += 256) Cs[e >> 4][e & (VSL - 1)] = 0.f;
    if (tid < Ksz) nS[tid] = 0.f;

    const float* mpb = mp + bh * (NT + 1);
    const size_t hbase = (size_t)bh * Tsz;

    for (int c = 0; c < NT; ++c) {
        float mpc = mpb[c], mpn = mpb[c + 1];
        float g = scaG[bh * NT + c];
        float dec = exp2f(g + mpc - mpn);
        if (tid < BT) {
            int t = bh * Tsz + c * BT + tid;
            float b = vecB[t];
            float mc = fmaxf(mpc + b, mintra[t]);
            sfq[tid] = SCALE * exp2f(b + mpc - mc);
            sfk[tid] = exp2f(vecA[t] - mpn);
        }
        __syncthreads();
        // stage qbar, kbar, v-slice
        const float* qrow = q + (hbase + c * BT) * Ksz;
        const float* krow = k + (hbase + c * BT) * Ksz;
        for (int e = tid; e < BT * Ksz; e += 256) {
            int i = e >> 7, kk = e & 127;
            qb[i][kk] = qrow[e] * sfq[i];
            kb[i][kk] = krow[e] * sfk[i];
        }
        const float* vrow = v + (hbase + c * BT) * Vsz + s * VSL;
        for (int e = tid; e < BT * VSL; e += 256) {
            int i = e >> 4, cc = e & (VSL - 1);
            vsl[i][cc] = vrow[(size_t)i * Vsz + cc];
        }
        __syncthreads();
        // consumption: out = qbar @ Cp (2 rows x 2 cols per thread)
        {
            int r0 = (tid >> 3) * 2, c0 = (tid & 7) * 2;
            float a00 = 0.f, a01 = 0.f, a10 = 0.f, a11 = 0.f;
            #pragma unroll 8
            for (int kk = 0; kk < Ksz; ++kk) {
                float q0 = qb[r0][kk], q1 = qb[r0 + 1][kk];
                float c0v = Cs[kk][c0], c1v = Cs[kk][c0 + 1];
                a00 += q0 * c0v; a01 += q0 * c1v;
                a10 += q1 * c0v; a11 += q1 * c1v;
            }
            size_t ob = (hbase + c * BT) * Vsz + s * VSL;
            out[ob + (size_t)r0 * Vsz + c0]           = a00;
            out[ob + (size_t)r0 * Vsz + c0 + 1]       = a01;
            out[ob + (size_t)(r0 + 1) * Vsz + c0]     = a10;
            out[ob + (size_t)(r0 + 1) * Vsz + c0 + 1] = a11;
        }
        if (s == 0 && tid < BT) {  // den_inter = qbar . np (pre-update n)
            float d = 0.f;
            for (int kk = 0; kk < Ksz; ++kk) d += qb[tid][kk] * nS[kk];
            denI[bh * Tsz + c * BT + tid] = d;
        }
        __syncthreads();
        // update: C = C*dec + kbar^T @ v  (2 k-rows x 4 v-cols per thread)
        {
            int kr = (tid >> 2) * 2, vc = (tid & 3) * 4;
            float u00 = 0, u01 = 0, u02 = 0, u03 = 0, u10 = 0, u11 = 0, u12 = 0, u13 = 0;
            #pragma unroll 4
            for (int j = 0; j < BT; ++j) {
                float k0 = kb[j][kr], k1 = kb[j][kr + 1];
                float v0 = vsl[j][vc], v1 = vsl[j][vc + 1], v2 = vsl[j][vc + 2], v3 = vsl[j][vc + 3];
                u00 += k0 * v0; u01 += k0 * v1; u02 += k0 * v2; u03 += k0 * v3;
                u10 += k1 * v0; u11 += k1 * v1; u12 += k1 * v2; u13 += k1 * v3;
            }
            Cs[kr][vc]         = Cs[kr][vc] * dec + u00;
            Cs[kr][vc + 1]     = Cs[kr][vc + 1] * dec + u01;
            Cs[kr][vc + 2]     = Cs[kr][vc + 2] * dec + u02;
            Cs[kr][vc + 3]     = Cs[kr][vc + 3] * dec + u03;
            Cs[kr + 1][vc]     = Cs[kr + 1][vc] * dec + u10;
            Cs[kr + 1][vc + 1] = Cs[kr + 1][vc + 1] * dec + u11;
            Cs[kr + 1][vc + 2] = Cs[kr + 1][vc + 2] * dec + u12;
            Cs[kr + 1][vc + 3] = Cs[kr + 1][vc + 3] * dec + u13;
        }
        if (s == 0 && tid < Ksz) {
            float sum = 0.f;
            for (int j = 0; j < BT; ++j) sum += kb[j][tid];
            nS[tid] = nS[tid] * dec + sum;
        }
        __syncthreads();
    }
}

// ---------------- kernel 4: intra-chunk attention + normalization ----------------
// One block per (bh, chunk). Reads inter contribution from `out`, adds S@v, normalizes.
__global__ __launch_bounds__(256) void k_intra(
    const float* __restrict__ q, const float* __restrict__ k, const float* __restrict__ v,
    const float* __restrict__ vecB, const float* __restrict__ vecI,
    const float* __restrict__ mintra, const float* __restrict__ mp,
    const float* __restrict__ denI, float* __restrict__ out)
{
    int c = blockIdx.x, bh = blockIdx.y, tid = threadIdx.x;
    __shared__ float qs[BT][Ksz + 1];
    __shared__ float ks[BT][Ksz + 1];
    __shared__ float vls[BT][Vsz + 1];
    __shared__ float Ss[BT][BT + 1];
    __shared__ float rowf[BT], colf[BT], mcomb[BT], rsum[BT];

    size_t hbase = (size_t)bh * Tsz;
    float mpc = mp[bh * (NT + 1) + c];
    if (tid < BT) {
        int t = bh * Tsz + c * BT + tid;
        float b = vecB[t];
        float mc = fmaxf(mpc + b, mintra[t]);
        mcomb[tid] = mc;
        rowf[tid] = SCALE * exp2f(b - mc);
        colf[tid] = exp2f(vecI[t] - b);
    }
    const float* qrow = q + (hbase + c * BT) * Ksz;
    const float* krow = k + (hbase + c * BT) * Ksz;
    const float* vrow = v + (hbase + c * BT) * Vsz;
    for (int e = tid; e < BT * Ksz; e += 256) {
        int i = e >> 7, kk = e & 127;
        qs[i][kk] = qrow[e];
        ks[i][kk] = krow[e];
        vls[i][kk] = vrow[e];
    }
    __syncthreads();
    // S = (q k^T) * scale * D  (4x4 tile per thread)
    {
        int r0 = (tid >> 4) * 4, c0 = (tid & 15) * 4;
        float acc[4][4];
        #pragma unroll
        for (int r = 0; r < 4; ++r)
            #pragma unroll
            for (int cc = 0; cc < 4; ++cc) acc[r][cc] = 0.f;
        for (int kk = 0; kk < Ksz; ++kk) {
            float qv[4], kv[4];
            #pragma unroll
            for (int r = 0; r < 4; ++r) qv[r] = qs[r0 + r][kk];
            #pragma unroll
            for (int cc = 0; cc < 4; ++cc) kv[cc] = ks[c0 + cc][kk];
            #pragma unroll
            for (int r = 0; r < 4; ++r)
                #pragma unroll
                for (int cc = 0; cc < 4; ++cc) acc[r][cc] += qv[r] * kv[cc];
        }
        #pragma unroll
        for (int r = 0; r < 4; ++r) {
            int i = r0 + r;
            float rf = rowf[i];
            #pragma unroll
            for (int cc = 0; cc < 4; ++cc) {
                int j = c0 + cc;
                Ss[i][j] = (j <= i) ? acc[r][cc] * rf * colf[j] : 0.f;
            }
        }
    }
    __syncthreads();
    if (tid < BT) {
        float sm = 0.f;
        for (int j = 0; j < BT; ++j) sm += Ss[tid][j];
        rsum[tid] = sm;
    }
    __syncthreads();
    // h = (inter + S@v) / norm   (4 rows x 8 strided cols per thread)
    {
        int r0 = (tid >> 4) * 4, tc = tid & 15;
        float acc[4][8];
        #pragma unroll
        for (int r = 0; r < 4; ++r)
            #pragma unroll
            for (int cc = 0; cc < 8; ++cc) acc[r][cc] = 0.f;
        for (int j = 0; j < BT; ++j) {
            float sv[4];
            #pragma unroll
            for (int r = 0; r < 4; ++r) sv[r] = Ss[r0 + r][j];
            #pragma unroll
            for (int cc = 0; cc < 8; ++cc) {
                float vv = vls[j][tc + 16 * cc];
                #pragma unroll
                for (int r = 0; r < 4; ++r) acc[r][cc] += sv[r] * vv;
            }
        }
        size_t ob = (hbase + c * BT) * Vsz;
        #pragma unroll
        for (int r = 0; r < 4; ++r) {
            int i = r0 + r;
            float den = denI[bh * Tsz + c * BT + i] + rsum[i];
            float inv = 1.f / fmaxf(fabsf(den), exp2f(-mcomb[i]));
            #pragma unroll
            for (int cc = 0; cc < 8; ++cc) {
                size_t idx = ob + (size_t)i * Vsz + tc + 16 * cc;
                out[idx] = (out[idx] + acc[r][cc]) * inv;
            }
        }
    }
}

extern "C" void kernel_launch(void* const* d_in, const int* in_sizes, int n_in,
                              void* d_out, int out_size, void* d_ws, size_t ws_size,
                              hipStream_t stream) {
    const float* q  = (const float*)d_in[0];
    const float* k  = (const float*)d_in[1];
    const float* v  = (const float*)d_in[2];
    const float* ig = (const float*)d_in[3];
    const float* fg = (const float*)d_in[4];
    float* out = (float*)d_out;

    float* ws = (float*)d_ws;
    float* vecB   = ws;                      // BH*T
    float* vecI   = vecB + BH * Tsz;         // BH*T
    float* vecA   = vecI + BH * Tsz;         // BH*T
    float* mintra = vecA + BH * Tsz;         // BH*T
    float* scaG   = mintra + BH * Tsz;       // BH*NT
    float* scaA   = scaG + BH * NT;          // BH*NT
    float* mp     = scaA + BH * NT;          // BH*(NT+1)
    float* denI   = mp + BH * (NT + 1);      // BH*T

    k_gates<<<dim3(NT, BH), 64, 0, stream>>>(ig, fg, vecB, vecI, vecA, mintra, scaG, scaA);
    k_mscan<<<dim3(BH), 64, 0, stream>>>(scaG, scaA, mp);
    k_inter<<<dim3(VS, BH), 256, 0, stream>>>(q, k, v, vecB, vecA, mintra, scaG, mp, denI, out);
    k_intra<<<dim3(NT, BH), 256, 0, stream>>>(q, k, v, vecB, vecI, mintra, mp, denI, out);
}

// Round 3
// 219.766 us; speedup vs baseline: 3.4461x; 3.4461x over previous
//
#include <hip/hip_runtime.h>
#include <hip/hip_bf16.h>
#include <math.h>

// mLSTM chunked forward. Round 3: parallel decomposition (U -> scan -> intra),
// split-bf16 MFMA for S (fp32-accurate), fp32 denominator path, MFMA S@v.
// B=4 H=8 T=4096 K=V=128, BT=64, NT=64.

#define LOG2E 1.4426950408889634f
constexpr int Bsz = 4, Hsz = 8, Tsz = 4096, Ksz = 128, Vsz = 128;
constexpr int BT = 64, NT = 64, BH = Bsz * Hsz;
constexpr float SCALE = 0.08838834764831845f; // 128^-0.5

typedef __attribute__((ext_vector_type(8))) short short8v;   // MFMA A/B frag (8 bf16)
typedef __attribute__((ext_vector_type(4))) float f32x4;     // MFMA C/D frag
typedef __attribute__((ext_vector_type(4))) unsigned short u16x4;
typedef __attribute__((ext_vector_type(8))) unsigned short u16x8;

__device__ inline float bf2f(unsigned short u) {
    union { unsigned int i; float f; } c; c.i = ((unsigned int)u) << 16; return c.f;
}
__device__ inline unsigned short f2bf(float f) {
    union { float f; unsigned int i; } c; c.f = f;
    unsigned int x = c.i;
    x += 0x7fffu + ((x >> 16) & 1u);      // round-to-nearest-even
    return (unsigned short)(x >> 16);
}

// ---------------- kernel 1: gate preprocessing per (bh, chunk) ----------------
__global__ __launch_bounds__(64) void k_gates(
    const float* __restrict__ ig, const float* __restrict__ fg,
    float* __restrict__ vecB, float* __restrict__ vecI, float* __restrict__ vecA,
    float* __restrict__ mintra, float* __restrict__ scaG, float* __restrict__ scaA)
{
    int c = blockIdx.x, bh = blockIdx.y, lane = threadIdx.x;
    int t = bh * Tsz + c * BT + lane;
    float f = fg[t];
    float ls = fminf(f, 0.f) - log1pf(expf(-fabsf(f)));  // stable log_sigmoid
    float vF = ls * LOG2E;
    float vI = ig[t] * LOG2E;
    float b = vF;
    #pragma unroll
    for (int off = 1; off < 64; off <<= 1) {
        float o = __shfl_up(b, off, 64);
        if (lane >= off) b += o;
    }
    float g = __shfl(b, 63, 64);
    float mi = vI - b;
    #pragma unroll
    for (int off = 1; off < 64; off <<= 1) {
        float o = __shfl_up(mi, off, 64);
        if (lane >= off) mi = fmaxf(mi, o);
    }
    float a = vI + g - b;
    vecB[t] = b; vecI[t] = vI; vecA[t] = a; mintra[t] = b + mi;
    float am = a;
    #pragma unroll
    for (int off = 32; off; off >>= 1) am = fmaxf(am, __shfl_xor(am, off, 64));
    if (lane == 0) { scaG[bh * NT + c] = g; scaA[bh * NT + c] = am; }
}

// ---------------- kernel 2: m stabilizer scan + per-chunk decay ----------------
__global__ __launch_bounds__(64) void k_mscan(
    const float* __restrict__ scaG, const float* __restrict__ scaA,
    float* __restrict__ mp, float* __restrict__ dec)
{
    int bh = blockIdx.x, lane = threadIdx.x;
    float g0 = scaG[bh * NT + lane];
    float a = g0, b = scaA[bh * NT + lane];
    #pragma unroll
    for (int off = 1; off < 64; off <<= 1) {
        float ap = __shfl_up(a, off, 64);
        float bp = __shfl_up(b, off, 64);
        if (lane >= off) { b = fmaxf(bp + a, b); a = ap + a; }
    }
    float m_incl = fmaxf(a, b);         // m after chunk `lane`
    float m_prev = __shfl_up(m_incl, 1, 64);
    if (lane == 0) { m_prev = 0.f; mp[bh * (NT + 1)] = 0.f; }
    mp[bh * (NT + 1) + lane + 1] = m_incl;
    dec[bh * NT + lane] = exp2f(g0 + m_prev - m_incl);
}

// ---------------- kernel 3: per-chunk state contribution U_c = kbar^T @ v ----------------
__global__ __launch_bounds__(256) void k_state(
    const float* __restrict__ kg, const float* __restrict__ vg,
    const float* __restrict__ vecA, const float* __restrict__ mp,
    unsigned short* __restrict__ UT, float* __restrict__ nU)
{
    int c = blockIdx.x, bh = blockIdx.y, tid = threadIdx.x;
    __shared__ float kb[BT][Ksz + 4];
    __shared__ float vs[BT][Vsz + 4];
    __shared__ float sfk[BT];
    size_t hb = (size_t)bh * Tsz + (size_t)c * BT;
    float mpn = mp[bh * (NT + 1) + c + 1];
    if (tid < BT) sfk[tid] = exp2f(vecA[hb + tid] - mpn);
    __syncthreads();
    const float4* k4 = (const float4*)(kg + hb * Ksz);
    const float4* v4 = (const float4*)(vg + hb * Vsz);
    for (int e = tid; e < BT * Ksz / 4; e += 256) {
        int i = e >> 5, c4 = (e & 31) * 4;
        float4 kv = k4[e]; float s = sfk[i];
        kb[i][c4] = kv.x * s; kb[i][c4 + 1] = kv.y * s;
        kb[i][c4 + 2] = kv.z * s; kb[i][c4 + 3] = kv.w * s;
        float4 vv = v4[e];
        vs[i][c4] = vv.x; vs[i][c4 + 1] = vv.y;
        vs[i][c4 + 2] = vv.z; vs[i][c4 + 3] = vv.w;
    }
    __syncthreads();
    int vc0 = (tid >> 4) * 8, k0 = (tid & 15) * 8;
    float acc[8][8];
    #pragma unroll
    for (int a = 0; a < 8; ++a)
        #pragma unroll
        for (int b = 0; b < 8; ++b) acc[a][b] = 0.f;
    for (int j = 0; j < BT; ++j) {
        float kv[8], vv[8];
        #pragma unroll
        for (int x = 0; x < 8; ++x) { kv[x] = kb[j][k0 + x]; vv[x] = vs[j][vc0 + x]; }
        #pragma unroll
        for (int vi = 0; vi < 8; ++vi)
            #pragma unroll
            for (int ki = 0; ki < 8; ++ki) acc[vi][ki] += vv[vi] * kv[ki];
    }
    unsigned short* Ub = UT + (size_t)(bh * NT + c) * (Ksz * Vsz);
    #pragma unroll
    for (int vi = 0; vi < 8; ++vi) {
        u16x8 w;
        #pragma unroll
        for (int ki = 0; ki < 8; ++ki) w[ki] = f2bf(acc[vi][ki]);
        *(u16x8*)(Ub + (size_t)(vc0 + vi) * Ksz + k0) = w;
    }
    if (tid < Ksz) {
        float s = 0.f;
        for (int j = 0; j < BT; ++j) s += kb[j][tid];
        nU[(size_t)(bh * NT + c) * Ksz + tid] = s;
    }
}

// ---------------- kernel 4: normalizer scan ----------------
__global__ __launch_bounds__(128) void k_nscan(
    const float* __restrict__ nU, const float* __restrict__ dec, float* __restrict__ np)
{
    int bh = blockIdx.x, tid = threadIdx.x;
    float n = 0.f;
    size_t base = (size_t)bh * NT * Ksz + tid;
    for (int c = 0; c < NT; ++c) {
        np[base + (size_t)c * Ksz] = n;
        n = n * dec[bh * NT + c] + nU[base + (size_t)c * Ksz];
    }
}

// ---------------- kernel 5: elementwise state scan, in place (U -> Cp) ----------------
__global__ __launch_bounds__(256) void k_scan(
    unsigned short* __restrict__ UT, const float* __restrict__ dec)
{
    int s = blockIdx.x, bh = blockIdx.y, tid = threadIdx.x;
    __shared__ float decs[NT];
    if (tid < NT) decs[tid] = dec[bh * NT + tid];
    __syncthreads();
    int vc = s * 8 + (tid >> 5), k0 = (tid & 31) * 4;
    size_t base = (size_t)bh * NT * (Ksz * Vsz) + (size_t)vc * Ksz + k0;
    float C0 = 0.f, C1 = 0.f, C2 = 0.f, C3 = 0.f;
    for (int c = 0; c < NT; ++c) {
        size_t idx = base + (size_t)c * (Ksz * Vsz);
        u16x4 u = *(const u16x4*)(UT + idx);
        u16x4 w;
        w.x = f2bf(C0); w.y = f2bf(C1); w.z = f2bf(C2); w.w = f2bf(C3);
        *(u16x4*)(UT + idx) = w;
        float d = decs[c];
        C0 = C0 * d + bf2f(u.x); C1 = C1 * d + bf2f(u.y);
        C2 = C2 * d + bf2f(u.z); C3 = C3 * d + bf2f(u.w);
    }
}

// ---------------- kernel 6: intra + consumption + normalize (split-bf16 precision) ----------------
__global__ __launch_bounds__(256) void k_intra(
    const float* __restrict__ qg, const float* __restrict__ kgl, const float* __restrict__ vg,
    const float* __restrict__ vecB, const float* __restrict__ vecI,
    const float* __restrict__ mintra, const float* __restrict__ mp,
    const float* __restrict__ np, const unsigned short* __restrict__ CpT,
    float* __restrict__ out)
{
    int c = blockIdx.x, bh = blockIdx.y, tid = threadIdx.x;
    int lane = tid & 63, wid = tid >> 6;
    int lrow = lane & 15, kgrp = lane >> 4;

    __shared__ unsigned short qhi[BT][Ksz + 8];
    __shared__ unsigned short qlo[BT][Ksz + 8];
    __shared__ unsigned short khi[BT][Ksz + 8];
    __shared__ unsigned short klo[BT][Ksz + 8];
    __shared__ unsigned short cps[Ksz][Ksz + 8];   // CpT[v][k] bf16
    __shared__ unsigned short vT[Vsz][BT + 8];     // v transposed [vcol][j]
    __shared__ unsigned short Sb[BT][BT + 8];      // S bf16 (PV operand)
    __shared__ float Ss[BT][BT + 1];               // S fp32 (rowsum)
    __shared__ float rowf[BT], colf[BT], sfq[BT], denb[BT], npv[Ksz];

    size_t hb = (size_t)bh * Tsz + (size_t)c * BT;
    float mpc = mp[bh * (NT + 1) + c];
    float emc = 0.f;
    if (tid < BT) {
        float b = vecB[hb + tid];
        float mc = fmaxf(mpc + b, mintra[hb + tid]);
        rowf[tid] = SCALE * exp2f(b - mc);
        colf[tid] = exp2f(vecI[hb + tid] - b);
        sfq[tid]  = SCALE * exp2f(b + mpc - mc);
        emc = exp2f(-mc);
    }
    if (tid < Ksz) npv[tid] = np[((size_t)bh * NT + c) * Ksz + tid];

    // stage q/k split hi+lo, v transposed, Cp tile
    const float4* q4 = (const float4*)(qg + hb * Ksz);
    const float4* k4 = (const float4*)(kgl + hb * Ksz);
    const float4* v4 = (const float4*)(vg + hb * Vsz);
    for (int e = tid; e < BT * Ksz / 4; e += 256) {
        int i = e >> 5, c4 = (e & 31) * 4;
        float4 qv = q4[e];
        u16x4 h, l;
        h.x = f2bf(qv.x); l.x = f2bf(qv.x - bf2f(h.x));
        h.y = f2bf(qv.y); l.y = f2bf(qv.y - bf2f(h.y));
        h.z = f2bf(qv.z); l.z = f2bf(qv.z - bf2f(h.z));
        h.w = f2bf(qv.w); l.w = f2bf(qv.w - bf2f(h.w));
        *(u16x4*)&qhi[i][c4] = h; *(u16x4*)&qlo[i][c4] = l;
        float4 kv = k4[e];
        h.x = f2bf(kv.x); l.x = f2bf(kv.x - bf2f(h.x));
        h.y = f2bf(kv.y); l.y = f2bf(kv.y - bf2f(h.y));
        h.z = f2bf(kv.z); l.z = f2bf(kv.z - bf2f(h.z));
        h.w = f2bf(kv.w); l.w = f2bf(kv.w - bf2f(h.w));
        *(u16x4*)&khi[i][c4] = h; *(u16x4*)&klo[i][c4] = l;
        float4 vv = v4[e];
        vT[c4][i]     = f2bf(vv.x);
        vT[c4 + 1][i] = f2bf(vv.y);
        vT[c4 + 2][i] = f2bf(vv.z);
        vT[c4 + 3][i] = f2bf(vv.w);
    }
    const u16x8* Cg = (const u16x8*)(CpT + ((size_t)bh * NT + c) * (Ksz * Vsz));
    for (int e = tid; e < Ksz * Vsz / 8; e += 256) {
        int r = e >> 4, c8 = (e & 15) * 8;
        *(u16x8*)&cps[r][c8] = Cg[e];
    }
    __syncthreads();

    // ---- Phase A: S = q k^T at split-bf16 precision; inter = q @ Cp with split q ----
    f32x4 accS[4];
    #pragma unroll
    for (int jt = 0; jt < 4; ++jt) accS[jt] = (f32x4){0.f, 0.f, 0.f, 0.f};
    #pragma unroll
    for (int ks = 0; ks < 4; ++ks) {
        short8v ah = *(const short8v*)&qhi[wid * 16 + lrow][ks * 32 + kgrp * 8];
        short8v al = *(const short8v*)&qlo[wid * 16 + lrow][ks * 32 + kgrp * 8];
        #pragma unroll
        for (int jt = 0; jt < 4; ++jt) {
            if (jt <= wid) {
                short8v bh_ = *(const short8v*)&khi[jt * 16 + lrow][ks * 32 + kgrp * 8];
                short8v bl  = *(const short8v*)&klo[jt * 16 + lrow][ks * 32 + kgrp * 8];
                accS[jt] = __builtin_amdgcn_mfma_f32_16x16x32_bf16(ah, bh_, accS[jt], 0, 0, 0);
                accS[jt] = __builtin_amdgcn_mfma_f32_16x16x32_bf16(al, bh_, accS[jt], 0, 0, 0);
                accS[jt] = __builtin_amdgcn_mfma_f32_16x16x32_bf16(ah, bl,  accS[jt], 0, 0, 0);
            }
        }
    }
    f32x4 accC[8];
    #pragma unroll
    for (int vt = 0; vt < 8; ++vt) accC[vt] = (f32x4){0.f, 0.f, 0.f, 0.f};
    #pragma unroll
    for (int ks = 0; ks < 4; ++ks) {
        short8v ah = *(const short8v*)&qhi[wid * 16 + lrow][ks * 32 + kgrp * 8];
        short8v al = *(const short8v*)&qlo[wid * 16 + lrow][ks * 32 + kgrp * 8];
        #pragma unroll
        for (int vt = 0; vt < 8; ++vt) {
            short8v bc = *(const short8v*)&cps[vt * 16 + lrow][ks * 32 + kgrp * 8];
            accC[vt] = __builtin_amdgcn_mfma_f32_16x16x32_bf16(ah, bc, accC[vt], 0, 0, 0);
            accC[vt] = __builtin_amdgcn_mfma_f32_16x16x32_bf16(al, bc, accC[vt], 0, 0, 0);
        }
    }
    // mask + scale, write S fp32 (rowsum) and bf16 (PV operand)
    #pragma unroll
    for (int jt = 0; jt < 4; ++jt) {
        #pragma unroll
        for (int r = 0; r < 4; ++r) {
            int i = wid * 16 + kgrp * 4 + r;
            int j = jt * 16 + lrow;
            float val = (j <= i) ? accS[jt][r] * rowf[i] * colf[j] : 0.f;
            Ss[i][j] = val;
            Sb[i][j] = f2bf(val);
        }
    }
    __syncthreads();

    // ---- Phase B: denominator (wave 0, fp32) and S@v MFMA (all waves) ----
    if (tid < BT) {
        float sm = 0.f;
        for (int j = 0; j < BT; ++j) sm += Ss[tid][j];
        float di = 0.f;
        for (int kk = 0; kk < Ksz; ++kk) {
            float qf = bf2f(qhi[tid][kk]) + bf2f(qlo[tid][kk]);
            di += qf * npv[kk];
        }
        float den = sfq[tid] * di + sm;
        denb[tid] = 1.f / fmaxf(fabsf(den), emc);
    }
    f32x4 accV[8];
    #pragma unroll
    for (int vt = 0; vt < 8; ++vt) accV[vt] = (f32x4){0.f, 0.f, 0.f, 0.f};
    #pragma unroll
    for (int ks = 0; ks < 2; ++ks) {
        short8v as_ = *(const short8v*)&Sb[wid * 16 + lrow][ks * 32 + kgrp * 8];
        #pragma unroll
        for (int vt = 0; vt < 8; ++vt) {
            short8v bv = *(const short8v*)&vT[vt * 16 + lrow][ks * 32 + kgrp * 8];
            accV[vt] = __builtin_amdgcn_mfma_f32_16x16x32_bf16(as_, bv, accV[vt], 0, 0, 0);
        }
    }
    __syncthreads();

    // ---- Phase C: combine in registers + store ----
    size_t gb = hb * Vsz;
    #pragma unroll
    for (int vt = 0; vt < 8; ++vt) {
        #pragma unroll
        for (int r = 0; r < 4; ++r) {
            int i = wid * 16 + kgrp * 4 + r, vc = vt * 16 + lrow;
            out[gb + (size_t)i * Vsz + vc] = (sfq[i] * accC[vt][r] + accV[vt][r]) * denb[i];
        }
    }
}

extern "C" void kernel_launch(void* const* d_in, const int* in_sizes, int n_in,
                              void* d_out, int out_size, void* d_ws, size_t ws_size,
                              hipStream_t stream) {
    const float* q  = (const float*)d_in[0];
    const float* k  = (const float*)d_in[1];
    const float* v  = (const float*)d_in[2];
    const float* ig = (const float*)d_in[3];
    const float* fg = (const float*)d_in[4];
    float* out = (float*)d_out;

    float* ws = (float*)d_ws;
    float* vecB   = ws;                       // BH*T
    float* vecI   = vecB + BH * Tsz;          // BH*T
    float* vecA   = vecI + BH * Tsz;          // BH*T
    float* mintra = vecA + BH * Tsz;          // BH*T
    float* scaG   = mintra + BH * Tsz;        // BH*NT
    float* scaA   = scaG + BH * NT;           // BH*NT
    float* dec    = scaA + BH * NT;           // BH*NT
    float* mp     = dec + BH * NT;            // BH*(NT+1)
    float* nU     = mp + BH * (NT + 1);       // BH*NT*K
    float* np     = nU + BH * NT * Ksz;       // BH*NT*K
    unsigned short* UT = (unsigned short*)(np + BH * NT * Ksz);  // BH*NT*K*V bf16 (in-place U->Cp)

    k_gates<<<dim3(NT, BH), 64, 0, stream>>>(ig, fg, vecB, vecI, vecA, mintra, scaG, scaA);
    k_mscan<<<dim3(BH), 64, 0, stream>>>(scaG, scaA, mp, dec);
    k_state<<<dim3(NT, BH), 256, 0, stream>>>(k, v, vecA, mp, UT, nU);
    k_nscan<<<dim3(BH), 128, 0, stream>>>(nU, dec, np);
    k_scan<<<dim3(16, BH), 256, 0, stream>>>(UT, dec);
    k_intra<<<dim3(NT, BH), 256, 0, stream>>>(q, k, v, vecB, vecI, mintra, mp, np, UT, out);
}

// Round 4
// 142.658 us; speedup vs baseline: 5.3088x; 1.5405x over previous
//
#include <hip/hip_runtime.h>
#include <hip/hip_bf16.h>
#include <math.h>

// mLSTM chunked forward. Round 4: occupancy rework.
// k_intra: 70 KB LDS (union phase-A/phase-B tiles), q in registers, in-reg rowsum -> 2 blocks/CU.
// k_state: MFMA (v^T x kbar^T with split-kbar precision).
// B=4 H=8 T=4096 K=V=128, BT=64, NT=64.

#define LOG2E 1.4426950408889634f
constexpr int Bsz = 4, Hsz = 8, Tsz = 4096, Ksz = 128, Vsz = 128;
constexpr int BT = 64, NT = 64, BH = Bsz * Hsz;
constexpr float SCALE = 0.08838834764831845f; // 128^-0.5

typedef __attribute__((ext_vector_type(8))) short short8v;   // MFMA A/B frag (8 bf16)
typedef __attribute__((ext_vector_type(4))) float f32x4;     // MFMA C/D frag
typedef __attribute__((ext_vector_type(4))) unsigned short u16x4;
typedef __attribute__((ext_vector_type(8))) unsigned short u16x8;

__device__ inline float bf2f(unsigned short u) {
    union { unsigned int i; float f; } c; c.i = ((unsigned int)u) << 16; return c.f;
}
__device__ inline unsigned short f2bf(float f) {
    union { float f; unsigned int i; } c; c.f = f;
    unsigned int x = c.i;
    x += 0x7fffu + ((x >> 16) & 1u);      // round-to-nearest-even
    return (unsigned short)(x >> 16);
}

// ---------------- kernel 1: gate preprocessing per (bh, chunk) ----------------
__global__ __launch_bounds__(64) void k_gates(
    const float* __restrict__ ig, const float* __restrict__ fg,
    float* __restrict__ vecB, float* __restrict__ vecI, float* __restrict__ vecA,
    float* __restrict__ mintra, float* __restrict__ scaG, float* __restrict__ scaA)
{
    int c = blockIdx.x, bh = blockIdx.y, lane = threadIdx.x;
    int t = bh * Tsz + c * BT + lane;
    float f = fg[t];
    float ls = fminf(f, 0.f) - log1pf(expf(-fabsf(f)));  // stable log_sigmoid
    float vF = ls * LOG2E;
    float vI = ig[t] * LOG2E;
    float b = vF;
    #pragma unroll
    for (int off = 1; off < 64; off <<= 1) {
        float o = __shfl_up(b, off, 64);
        if (lane >= off) b += o;
    }
    float g = __shfl(b, 63, 64);
    float mi = vI - b;
    #pragma unroll
    for (int off = 1; off < 64; off <<= 1) {
        float o = __shfl_up(mi, off, 64);
        if (lane >= off) mi = fmaxf(mi, o);
    }
    float a = vI + g - b;
    vecB[t] = b; vecI[t] = vI; vecA[t] = a; mintra[t] = b + mi;
    float am = a;
    #pragma unroll
    for (int off = 32; off; off >>= 1) am = fmaxf(am, __shfl_xor(am, off, 64));
    if (lane == 0) { scaG[bh * NT + c] = g; scaA[bh * NT + c] = am; }
}

// ---------------- kernel 2: m stabilizer scan + per-chunk decay ----------------
__global__ __launch_bounds__(64) void k_mscan(
    const float* __restrict__ scaG, const float* __restrict__ scaA,
    float* __restrict__ mp, float* __restrict__ dec)
{
    int bh = blockIdx.x, lane = threadIdx.x;
    float g0 = scaG[bh * NT + lane];
    float a = g0, b = scaA[bh * NT + lane];
    #pragma unroll
    for (int off = 1; off < 64; off <<= 1) {
        float ap = __shfl_up(a, off, 64);
        float bp = __shfl_up(b, off, 64);
        if (lane >= off) { b = fmaxf(bp + a, b); a = ap + a; }
    }
    float m_incl = fmaxf(a, b);
    float m_prev = __shfl_up(m_incl, 1, 64);
    if (lane == 0) { m_prev = 0.f; mp[bh * (NT + 1)] = 0.f; }
    mp[bh * (NT + 1) + lane + 1] = m_incl;
    dec[bh * NT + lane] = exp2f(g0 + m_prev - m_incl);
}

// ---------------- kernel 3: U^T = v^T @ kbar (MFMA, split-kbar) ----------------
// One block per (bh, chunk). Stages kbar^T hi/lo and v^T via register 4x4 transposes,
// computes UT[v][k] = sum_j v[j][v]*kbar[j][k] with 16x16x32 MFMA, writes bf16.
__global__ __launch_bounds__(256, 2) void k_state(
    const float* __restrict__ kg, const float* __restrict__ vg,
    const float* __restrict__ vecA, const float* __restrict__ mp,
    unsigned short* __restrict__ UT, float* __restrict__ nU)
{
    int c = blockIdx.x, bh = blockIdx.y, tid = threadIdx.x;
    int lane = tid & 63, wid = tid >> 6;
    int lrow = lane & 15, kgrp = lane >> 4;

    __shared__ __align__(16) unsigned short kThi[128][72];  // kbar^T hi  [k][j]
    __shared__ __align__(16) unsigned short kTlo[128][72];  // kbar^T lo
    __shared__ __align__(16) unsigned short vTs[128][72];   // v^T        [v][j]
    __shared__ float sfk[BT];

    size_t hb = (size_t)bh * Tsz + (size_t)c * BT;
    float mpn = mp[bh * (NT + 1) + c + 1];
    if (tid < BT) sfk[tid] = exp2f(vecA[hb + tid] - mpn);
    __syncthreads();

    int cb = tid & 15, jb = tid >> 4;     // col-block (of 4), j-block (of 4)
    #pragma unroll
    for (int p = 0; p < 2; ++p) {
        int c0 = p * 64 + cb * 4;
        float ka[4][4], va[4][4], s[4];
        #pragma unroll
        for (int x = 0; x < 4; ++x) {
            float4 kr = *(const float4*)(kg + (hb + jb * 4 + x) * Ksz + c0);
            float4 vr = *(const float4*)(vg + (hb + jb * 4 + x) * Vsz + c0);
            ka[x][0] = kr.x; ka[x][1] = kr.y; ka[x][2] = kr.z; ka[x][3] = kr.w;
            va[x][0] = vr.x; va[x][1] = vr.y; va[x][2] = vr.z; va[x][3] = vr.w;
            s[x] = sfk[jb * 4 + x];
        }
        #pragma unroll
        for (int y = 0; y < 4; ++y) {
            u16x4 h, l, w;
            #pragma unroll
            for (int x = 0; x < 4; ++x) {
                float f = ka[x][y] * s[x];
                unsigned short hh = f2bf(f);
                h[x] = hh;
                l[x] = f2bf(f - bf2f(hh));
                w[x] = f2bf(va[x][y]);
            }
            *(u16x4*)&kThi[c0 + y][jb * 4] = h;
            *(u16x4*)&kTlo[c0 + y][jb * 4] = l;
            *(u16x4*)&vTs[c0 + y][jb * 4] = w;
        }
    }
    __syncthreads();

    // wave owns v-tiles {2*wid, 2*wid+1} x all 8 k-tiles
    f32x4 acc[2][8];
    #pragma unroll
    for (int vt = 0; vt < 2; ++vt)
        #pragma unroll
        for (int kt = 0; kt < 8; ++kt) acc[vt][kt] = (f32x4){0.f, 0.f, 0.f, 0.f};
    #pragma unroll
    for (int ks = 0; ks < 2; ++ks) {
        #pragma unroll
        for (int vt = 0; vt < 2; ++vt) {
            short8v af = *(const short8v*)&vTs[(wid * 2 + vt) * 16 + lrow][ks * 32 + kgrp * 8];
            #pragma unroll
            for (int kt = 0; kt < 8; ++kt) {
                short8v bh_ = *(const short8v*)&kThi[kt * 16 + lrow][ks * 32 + kgrp * 8];
                short8v bl  = *(const short8v*)&kTlo[kt * 16 + lrow][ks * 32 + kgrp * 8];
                acc[vt][kt] = __builtin_amdgcn_mfma_f32_16x16x32_bf16(af, bh_, acc[vt][kt], 0, 0, 0);
                acc[vt][kt] = __builtin_amdgcn_mfma_f32_16x16x32_bf16(af, bl,  acc[vt][kt], 0, 0, 0);
            }
        }
    }
    unsigned short* Ub = UT + (size_t)(bh * NT + c) * (Ksz * Vsz);
    #pragma unroll
    for (int vt = 0; vt < 2; ++vt)
        #pragma unroll
        for (int kt = 0; kt < 8; ++kt)
            #pragma unroll
            for (int r = 0; r < 4; ++r) {
                int vc = (wid * 2 + vt) * 16 + kgrp * 4 + r;
                int kk = kt * 16 + lrow;
                Ub[(size_t)vc * Ksz + kk] = f2bf(acc[vt][kt][r]);
            }
    // nU[kk] = sum_j kbar[j][kk]  (hi+lo reconstruction, fp32)
    if (tid < Ksz) {
        float ssum = 0.f;
        for (int j = 0; j < BT; ++j) ssum += bf2f(kThi[tid][j]) + bf2f(kTlo[tid][j]);
        nU[(size_t)(bh * NT + c) * Ksz + tid] = ssum;
    }
}

// ---------------- kernel 4: normalizer scan ----------------
__global__ __launch_bounds__(128) void k_nscan(
    const float* __restrict__ nU, const float* __restrict__ dec, float* __restrict__ np)
{
    int bh = blockIdx.x, tid = threadIdx.x;
    float n = 0.f;
    size_t base = (size_t)bh * NT * Ksz + tid;
    for (int c = 0; c < NT; ++c) {
        np[base + (size_t)c * Ksz] = n;
        n = n * dec[bh * NT + c] + nU[base + (size_t)c * Ksz];
    }
}

// ---------------- kernel 5: elementwise state scan, in place (U -> Cp) ----------------
__global__ __launch_bounds__(256) void k_scan(
    unsigned short* __restrict__ UT, const float* __restrict__ dec)
{
    int s = blockIdx.x, bh = blockIdx.y, tid = threadIdx.x;
    __shared__ float decs[NT];
    if (tid < NT) decs[tid] = dec[bh * NT + tid];
    __syncthreads();
    int vc = s * 8 + (tid >> 5), k0 = (tid & 31) * 4;
    size_t base = (size_t)bh * NT * (Ksz * Vsz) + (size_t)vc * Ksz + k0;
    float C0 = 0.f, C1 = 0.f, C2 = 0.f, C3 = 0.f;
    for (int c = 0; c < NT; ++c) {
        size_t idx = base + (size_t)c * (Ksz * Vsz);
        u16x4 u = *(const u16x4*)(UT + idx);
        u16x4 w;
        w.x = f2bf(C0); w.y = f2bf(C1); w.z = f2bf(C2); w.w = f2bf(C3);
        *(u16x4*)(UT + idx) = w;
        float d = decs[c];
        C0 = C0 * d + bf2f(u.x); C1 = C1 * d + bf2f(u.y);
        C2 = C2 * d + bf2f(u.z); C3 = C3 * d + bf2f(u.w);
    }
}

// ---------------- kernel 6: intra + consumption + normalize ----------------
// 70 KB LDS: union{khi,klo | Sb,vT} + cps + scalars -> 2 blocks/CU.
__global__ __launch_bounds__(256, 2) void k_intra(
    const float* __restrict__ qg, const float* __restrict__ kgl, const float* __restrict__ vg,
    const float* __restrict__ vecB, const float* __restrict__ vecI,
    const float* __restrict__ mintra, const float* __restrict__ mp,
    const float* __restrict__ np, const unsigned short* __restrict__ CpT,
    float* __restrict__ out)
{
    int c = blockIdx.x, bh = blockIdx.y, tid = threadIdx.x;
    int lane = tid & 63, wid = tid >> 6;
    int lrow = lane & 15, kgrp = lane >> 4;

    __shared__ __align__(16) unsigned short uA[64 * 136 * 2]; // union region (34816 B)
    __shared__ __align__(16) unsigned short cps_[128][136];   // Cp^T [v][k]
    __shared__ float rowf[BT], colf[BT], sfqs[BT], emcs[BT], denb[BT], npv[Ksz];

    auto khi = (unsigned short(*)[136])uA;              // phase A: k hi
    auto klo = (unsigned short(*)[136])(uA + 64 * 136); // phase A: k lo
    auto Sb  = (unsigned short(*)[72])uA;               // phase B: S bf16
    auto vT  = (unsigned short(*)[72])(uA + 64 * 72);   // phase B: v^T

    size_t hb = (size_t)bh * Tsz + (size_t)c * BT;
    float mpc = mp[bh * (NT + 1) + c];
    if (tid < BT) {
        float b = vecB[hb + tid];
        float mc = fmaxf(mpc + b, mintra[hb + tid]);
        rowf[tid] = SCALE * exp2f(b - mc);
        colf[tid] = exp2f(vecI[hb + tid] - b);
        sfqs[tid] = SCALE * exp2f(b + mpc - mc);
        emcs[tid] = exp2f(-mc);
    }
    if (tid < Ksz) npv[tid] = np[((size_t)bh * NT + c) * Ksz + tid];

    // stage k hi/lo
    const float4* k4 = (const float4*)(kgl + hb * Ksz);
    for (int e = tid; e < BT * Ksz / 4; e += 256) {
        int i = e >> 5, c4 = (e & 31) * 4;
        float4 kv = k4[e];
        u16x4 h, l;
        h.x = f2bf(kv.x); l.x = f2bf(kv.x - bf2f(h.x));
        h.y = f2bf(kv.y); l.y = f2bf(kv.y - bf2f(h.y));
        h.z = f2bf(kv.z); l.z = f2bf(kv.z - bf2f(h.z));
        h.w = f2bf(kv.w); l.w = f2bf(kv.w - bf2f(h.w));
        *(u16x4*)&khi[i][c4] = h; *(u16x4*)&klo[i][c4] = l;
    }
    // stage Cp
    const u16x8* Cg = (const u16x8*)(CpT + ((size_t)bh * NT + c) * (Ksz * Vsz));
    for (int e = tid; e < Ksz * Vsz / 8; e += 256) {
        int r = e >> 4, c8 = (e & 15) * 8;
        *(u16x8*)&cps_[r][c8] = Cg[e];
    }
    // q rows (wave-local) into fp32 registers
    const float* qrow = qg + (hb + wid * 16 + lrow) * Ksz;
    float qf[4][8];
    #pragma unroll
    for (int ks = 0; ks < 4; ++ks) {
        float4 a = *(const float4*)(qrow + ks * 32 + kgrp * 8);
        float4 b = *(const float4*)(qrow + ks * 32 + kgrp * 8 + 4);
        qf[ks][0] = a.x; qf[ks][1] = a.y; qf[ks][2] = a.z; qf[ks][3] = a.w;
        qf[ks][4] = b.x; qf[ks][5] = b.y; qf[ks][6] = b.z; qf[ks][7] = b.w;
    }
    // v prefetch to registers (written to vT after the union barrier)
    int vcb = tid & 15, jb = tid >> 4;
    float vpre[2][4][4];
    #pragma unroll
    for (int p = 0; p < 2; ++p)
        #pragma unroll
        for (int x = 0; x < 4; ++x) {
            float4 t = *(const float4*)(vg + (hb + jb * 4 + x) * Vsz + p * 64 + vcb * 4);
            vpre[p][x][0] = t.x; vpre[p][x][1] = t.y; vpre[p][x][2] = t.z; vpre[p][x][3] = t.w;
        }
    __syncthreads();

    // denominator inter part: qdot = sfq[row] * (q[row] . np), fp32
    float dot = 0.f;
    #pragma unroll
    for (int ks = 0; ks < 4; ++ks)
        #pragma unroll
        for (int x = 0; x < 8; ++x) dot += qf[ks][x] * npv[ks * 32 + kgrp * 8 + x];
    dot += __shfl_xor(dot, 16, 64);
    dot += __shfl_xor(dot, 32, 64);
    float qdot = sfqs[wid * 16 + lrow] * dot;

    // q -> hi/lo MFMA fragments
    short8v qh[4], ql[4];
    #pragma unroll
    for (int ks = 0; ks < 4; ++ks)
        #pragma unroll
        for (int x = 0; x < 8; ++x) {
            float f = qf[ks][x];
            unsigned short hh = f2bf(f);
            qh[ks][x] = (short)hh;
            ql[ks][x] = (short)f2bf(f - bf2f(hh));
        }

    // ---- Phase A: S = q k^T (3-way split); inter = q @ Cp (2-way split) ----
    f32x4 accS[4];
    #pragma unroll
    for (int jt = 0; jt < 4; ++jt) accS[jt] = (f32x4){0.f, 0.f, 0.f, 0.f};
    #pragma unroll
    for (int ks = 0; ks < 4; ++ks) {
        #pragma unroll
        for (int jt = 0; jt < 4; ++jt) {
            if (jt <= wid) {
                short8v bh_ = *(const short8v*)&khi[jt * 16 + lrow][ks * 32 + kgrp * 8];
                short8v bl  = *(const short8v*)&klo[jt * 16 + lrow][ks * 32 + kgrp * 8];
                accS[jt] = __builtin_amdgcn_mfma_f32_16x16x32_bf16(qh[ks], bh_, accS[jt], 0, 0, 0);
                accS[jt] = __builtin_amdgcn_mfma_f32_16x16x32_bf16(ql[ks], bh_, accS[jt], 0, 0, 0);
                accS[jt] = __builtin_amdgcn_mfma_f32_16x16x32_bf16(qh[ks], bl,  accS[jt], 0, 0, 0);
            }
        }
    }
    f32x4 accC[8];
    #pragma unroll
    for (int vt = 0; vt < 8; ++vt) accC[vt] = (f32x4){0.f, 0.f, 0.f, 0.f};
    #pragma unroll
    for (int ks = 0; ks < 4; ++ks) {
        #pragma unroll
        for (int vt = 0; vt < 8; ++vt) {
            short8v bc = *(const short8v*)&cps_[vt * 16 + lrow][ks * 32 + kgrp * 8];
            accC[vt] = __builtin_amdgcn_mfma_f32_16x16x32_bf16(qh[ks], bc, accC[vt], 0, 0, 0);
            accC[vt] = __builtin_amdgcn_mfma_f32_16x16x32_bf16(ql[ks], bc, accC[vt], 0, 0, 0);
        }
    }

    // mask + scale in regs; in-register rowsum; denominator
    float rsum[4] = {0.f, 0.f, 0.f, 0.f};
    unsigned short sreg[4][4];
    #pragma unroll
    for (int jt = 0; jt < 4; ++jt)
        #pragma unroll
        for (int r = 0; r < 4; ++r) {
            int i = wid * 16 + kgrp * 4 + r, j = jt * 16 + lrow;
            float val = (j <= i) ? accS[jt][r] * rowf[i] * colf[j] : 0.f;
            rsum[r] += val;
            sreg[jt][r] = f2bf(val);
        }
    #pragma unroll
    for (int r = 0; r < 4; ++r) {
        rsum[r] += __shfl_xor(rsum[r], 1, 64);
        rsum[r] += __shfl_xor(rsum[r], 2, 64);
        rsum[r] += __shfl_xor(rsum[r], 4, 64);
        rsum[r] += __shfl_xor(rsum[r], 8, 64);
    }
    float qd[4];
    #pragma unroll
    for (int r = 0; r < 4; ++r) qd[r] = __shfl(qdot, kgrp * 4 + r, 64);
    if (lrow == 0) {
        #pragma unroll
        for (int r = 0; r < 4; ++r) {
            int i = wid * 16 + kgrp * 4 + r;
            float den = qd[r] + rsum[r];
            denb[i] = 1.f / fmaxf(fabsf(den), emcs[i]);
        }
    }
    __syncthreads();   // all phase-A reads of khi/klo done -> union reuse safe

    // union writes: Sb (from sreg) + vT (from vpre)
    #pragma unroll
    for (int jt = 0; jt < 4; ++jt)
        #pragma unroll
        for (int r = 0; r < 4; ++r)
            Sb[wid * 16 + kgrp * 4 + r][jt * 16 + lrow] = sreg[jt][r];
    #pragma unroll
    for (int p = 0; p < 2; ++p)
        #pragma unroll
        for (int y = 0; y < 4; ++y) {
            u16x4 w;
            #pragma unroll
            for (int x = 0; x < 4; ++x) w[x] = f2bf(vpre[p][x][y]);
            *(u16x4*)&vT[p * 64 + vcb * 4 + y][jb * 4] = w;
        }
    __syncthreads();

    // ---- Phase B: S @ v via MFMA ----
    f32x4 accV[8];
    #pragma unroll
    for (int vt = 0; vt < 8; ++vt) accV[vt] = (f32x4){0.f, 0.f, 0.f, 0.f};
    #pragma unroll
    for (int ks = 0; ks < 2; ++ks) {
        short8v as_ = *(const short8v*)&Sb[wid * 16 + lrow][ks * 32 + kgrp * 8];
        #pragma unroll
        for (int vt = 0; vt < 8; ++vt) {
            short8v bv = *(const short8v*)&vT[vt * 16 + lrow][ks * 32 + kgrp * 8];
            accV[vt] = __builtin_amdgcn_mfma_f32_16x16x32_bf16(as_, bv, accV[vt], 0, 0, 0);
        }
    }

    // ---- Phase C: combine + normalize + store ----
    size_t gb = hb * Vsz;
    #pragma unroll
    for (int vt = 0; vt < 8; ++vt)
        #pragma unroll
        for (int r = 0; r < 4; ++r) {
            int i = wid * 16 + kgrp * 4 + r, vc = vt * 16 + lrow;
            out[gb + (size_t)i * Vsz + vc] = (sfqs[i] * accC[vt][r] + accV[vt][r]) * denb[i];
        }
}

extern "C" void kernel_launch(void* const* d_in, const int* in_sizes, int n_in,
                              void* d_out, int out_size, void* d_ws, size_t ws_size,
                              hipStream_t stream) {
    const float* q  = (const float*)d_in[0];
    const float* k  = (const float*)d_in[1];
    const float* v  = (const float*)d_in[2];
    const float* ig = (const float*)d_in[3];
    const float* fg = (const float*)d_in[4];
    float* out = (float*)d_out;

    float* ws = (float*)d_ws;
    float* vecB   = ws;                       // BH*T
    float* vecI   = vecB + BH * Tsz;          // BH*T
    float* vecA   = vecI + BH * Tsz;          // BH*T
    float* mintra = vecA + BH * Tsz;          // BH*T
    float* scaG   = mintra + BH * Tsz;        // BH*NT
    float* scaA   = scaG + BH * NT;           // BH*NT
    float* dec    = scaA + BH * NT;           // BH*NT
    float* mp     = dec + BH * NT;            // BH*(NT+1)
    float* nU     = mp + BH * (NT + 1);       // BH*NT*K
    float* np     = nU + BH * NT * Ksz;       // BH*NT*K
    unsigned short* UT = (unsigned short*)(np + BH * NT * Ksz);  // BH*NT*K*V bf16 (in-place U->Cp)

    k_gates<<<dim3(NT, BH), 64, 0, stream>>>(ig, fg, vecB, vecI, vecA, mintra, scaG, scaA);
    k_mscan<<<dim3(BH), 64, 0, stream>>>(scaG, scaA, mp, dec);
    k_state<<<dim3(NT, BH), 256, 0, stream>>>(k, v, vecA, mp, UT, nU);
    k_nscan<<<dim3(BH), 128, 0, stream>>>(nU, dec, np);
    k_scan<<<dim3(16, BH), 256, 0, stream>>>(UT, dec);
    k_intra<<<dim3(NT, BH), 256, 0, stream>>>(q, k, v, vecB, vecI, mintra, mp, np, UT, out);
}